// Round 3
// baseline (312.900 us; speedup 1.0000x reference)
//
#include <hip/hip_runtime.h>

#define B_ 4
#define T_ 2048
#define C_ 1024
#define H_ 16
#define D_ 64
#define EPS_ 1.1920929e-07f
#define LOG2E_ 1.4426950408889634f

typedef __attribute__((ext_vector_type(8))) short bf16x8;
typedef __attribute__((ext_vector_type(4))) float f32x4;
typedef __attribute__((ext_vector_type(16))) float f32x16;
typedef unsigned short u16;
typedef unsigned int u32;
typedef __attribute__((ext_vector_type(4))) u32 u32x4;

__device__ inline u16 f2bf(float f) {
  unsigned u = __float_as_uint(f);
  unsigned r = (u + 0x7fffu + ((u >> 16) & 1u)) >> 16;
  return (u16)r;
}

// async global->LDS, 16B per lane (dest = wave-uniform base + lane*16)
__device__ __forceinline__ void gload16(const void* g, void* l) {
  __builtin_amdgcn_global_load_lds(
      (__attribute__((address_space(1))) void*)g,
      (__attribute__((address_space(3))) void*)l, 16, 0, 0);
}

// ---------------- f32 -> bf16 conversion (x) ----------------
__global__ __launch_bounds__(256) void cvt_bf16(const float* __restrict__ src,
                                                u16* __restrict__ dst, int n) {
  const int i = (blockIdx.x * 256 + threadIdx.x) * 4;
  if (i < n) {
    float4 v = *(const float4*)&src[i];
    ushort4 o;
    o.x = f2bf(v.x); o.y = f2bf(v.y); o.z = f2bf(v.z); o.w = f2bf(v.w);
    *(ushort4*)&dst[i] = o;
  }
}

// ---------------- all 4 weights in one launch ----------------
__global__ __launch_bounds__(256) void cvt_weights(const float* __restrict__ wq,
                                                   const float* __restrict__ wk,
                                                   const float* __restrict__ wv,
                                                   const float* __restrict__ wo,
                                                   u16* __restrict__ wqkv,
                                                   u16* __restrict__ wob, int n) {
  const int i = (blockIdx.x * 256 + threadIdx.x) * 4;
  const int t = blockIdx.y;
  const float* src = (t == 0) ? wq : (t == 1) ? wk : (t == 2) ? wv : wo;
  u16* dst = (t == 3) ? wob : (wqkv + (size_t)t * n);
  if (i < n) {
    float4 v = *(const float4*)&src[i];
    ushort4 o;
    o.x = f2bf(v.x); o.y = f2bf(v.y); o.z = f2bf(v.z); o.w = f2bf(v.w);
    *(ushort4*)&dst[i] = o;
  }
}

// ---------------- fused QKV GEMM: [Q|K|V] = X @ Wqkv^T + epilogues ----------------
// blockIdx.x: 0..7 -> Q (rope+rms, *scale*log2e), 8..15 -> K (rope+rms),
// 16..23 -> V stored transposed + SLOT-permuted: vtb[(bh*64+d)*T + tile*64 + slot],
// slot(k) = (k&48)|((k&2)<<2)|((k&8)>>1)|((k&4)>>1)|(k&1)  -- matches the
// cvt_pk+permlane32_swap packing order of P in flash (key k -> pa k-slot).
__global__ __launch_bounds__(256) void gemm_qkv(const u16* __restrict__ X,
                                                const u16* __restrict__ W,
                                                u16* __restrict__ qb,
                                                u16* __restrict__ kb,
                                                u16* __restrict__ vtb,
                                                const float* __restrict__ cs,
                                                const float* __restrict__ sn,
                                                int M, int K) {
  __shared__ short As[128 * 64];
  __shared__ short Bs[128 * 64];
  const int tid = threadIdx.x;
  const int lane = tid & 63;
  const int w = tid >> 6;
  const int wr = w >> 1, wc = w & 1;
  const int m0 = blockIdx.y * 128, n0 = blockIdx.x * 128;
  const int lrow = lane >> 3;       // 0..7 within an 8-row chunk
  const int lcol = (lane & 7) * 8;  // u16 col within a 64-col row

  f32x4 acc[4][4];
#pragma unroll
  for (int mi = 0; mi < 4; ++mi)
#pragma unroll
    for (int ni = 0; ni < 4; ++ni)
      acc[mi][ni] = (f32x4){0.f, 0.f, 0.f, 0.f};

  const int r = lane & 15;
  const int quad = lane >> 4;

  for (int kt = 0; kt < K; kt += 64) {
#pragma unroll
    for (int i = 0; i < 4; ++i) {
      const int row = w * 32 + i * 8;  // wave-uniform LDS dest row
      gload16(&X[(size_t)(m0 + row + lrow) * K + kt + lcol], &As[row * 64]);
      gload16(&W[(size_t)(n0 + row + lrow) * K + kt + lcol], &Bs[row * 64]);
    }
    __syncthreads();
#pragma unroll
    for (int kc = 0; kc < 2; ++kc) {
      const int ko = kc * 32 + quad * 8;
      bf16x8 a[4], b[4];
#pragma unroll
      for (int mi = 0; mi < 4; ++mi)
        a[mi] = *(const bf16x8*)&As[(wr * 64 + mi * 16 + r) * 64 + ko];
#pragma unroll
      for (int ni = 0; ni < 4; ++ni)
        b[ni] = *(const bf16x8*)&Bs[(wc * 64 + ni * 16 + r) * 64 + ko];
#pragma unroll
      for (int mi = 0; mi < 4; ++mi)
#pragma unroll
        for (int ni = 0; ni < 4; ++ni)
          acc[mi][ni] = __builtin_amdgcn_mfma_f32_16x16x32_bf16(a[mi], b[ni], acc[mi][ni], 0, 0, 0);
    }
    __syncthreads();
  }

  const int which = blockIdx.x >> 3;                // 0=Q 1=K 2=V
  const int c0 = (blockIdx.x & 7) * 128 + wc * 64;  // column within tensor (one head/wave)

  if (which < 2) {
    u16* dst = (which == 0) ? qb : kb;
    // fused RoPE + RMSNorm; d = ni*16+r, pair (d,d+32) = (ni,ni+2) in-lane
#pragma unroll
    for (int mi = 0; mi < 4; ++mi)
#pragma unroll
      for (int j = 0; j < 4; ++j) {
        const int gr = m0 + wr * 64 + mi * 16 + quad * 4 + j;
        const int t = gr & (T_ - 1);
        float o[4];
#pragma unroll
        for (int ni = 0; ni < 2; ++ni) {
          const float c = cs[t * 32 + ni * 16 + r];
          const float s = sn[t * 32 + ni * 16 + r];
          const float x1 = acc[mi][ni][j], x2 = acc[mi][ni + 2][j];
          o[ni]     = x1 * c + x2 * s;
          o[ni + 2] = x2 * c - x1 * s;
        }
        float sq = o[0] * o[0] + o[1] * o[1] + o[2] * o[2] + o[3] * o[3];
        sq += __shfl_xor(sq, 1, 64);
        sq += __shfl_xor(sq, 2, 64);
        sq += __shfl_xor(sq, 4, 64);
        sq += __shfl_xor(sq, 8, 64);
        float rn = rsqrtf(sq * (1.0f / 64.0f) + EPS_);
        if (which == 0) rn *= 0.125f * LOG2E_;  // fold attn scale AND log2(e) into Q
#pragma unroll
        for (int ni = 0; ni < 4; ++ni)
          dst[(size_t)gr * C_ + c0 + ni * 16 + r] = f2bf(o[ni] * rn);
      }
  } else {
    // V: transposed + slot-permuted store. head h, d = ni*16+r.
    // key-in-tile = mi*16 + quad*4 + j -> slot = mi*16 + (j>>1)*8 + quad*2 + (j&1)
    // => (j=0,1) at slots qp,qp+1 and (j=2,3) at qp+8,qp+9 with qp=quad*2: two u32 stores.
    const int h = (blockIdx.x & 7) * 2 + wc;
    const int gr0 = m0 + wr * 64;
    const int bb = gr0 >> 11;         // batch (T_=2048)
    const int tbase = gr0 & (T_ - 1); // multiple of 64
#pragma unroll
    for (int ni = 0; ni < 4; ++ni) {
      const int d = ni * 16 + r;
      u16* rowp = &vtb[((size_t)((bb * H_ + h) * D_ + d)) * T_ + tbase];
#pragma unroll
      for (int mi = 0; mi < 4; ++mi) {
        u32 lo, hi2;
        asm("v_cvt_pk_bf16_f32 %0, %1, %2" : "=v"(lo) : "v"(acc[mi][ni][0]), "v"(acc[mi][ni][1]));
        asm("v_cvt_pk_bf16_f32 %0, %1, %2" : "=v"(hi2) : "v"(acc[mi][ni][2]), "v"(acc[mi][ni][3]));
        u16* p = rowp + mi * 16 + quad * 2;
        *(u32*)&p[0] = lo;
        *(u32*)&p[8] = hi2;
      }
    }
  }
}

// ---------------- output GEMM: out = Y @ Wo^T (fp32 out) ----------------
__global__ __launch_bounds__(256) void gemm_out(const u16* __restrict__ X,
                                                const u16* __restrict__ W,
                                                float* __restrict__ Y,
                                                int M, int N, int K) {
  __shared__ short As[128 * 64];
  __shared__ short Bs[128 * 64];
  const int tid = threadIdx.x;
  const int lane = tid & 63;
  const int w = tid >> 6;
  const int wr = w >> 1, wc = w & 1;
  const int m0 = blockIdx.y * 128, n0 = blockIdx.x * 128;
  const int lrow = lane >> 3;
  const int lcol = (lane & 7) * 8;

  f32x4 acc[4][4];
#pragma unroll
  for (int mi = 0; mi < 4; ++mi)
#pragma unroll
    for (int ni = 0; ni < 4; ++ni)
      acc[mi][ni] = (f32x4){0.f, 0.f, 0.f, 0.f};

  const int r = lane & 15;
  const int quad = lane >> 4;

  for (int kt = 0; kt < K; kt += 64) {
#pragma unroll
    for (int i = 0; i < 4; ++i) {
      const int row = w * 32 + i * 8;
      gload16(&X[(size_t)(m0 + row + lrow) * K + kt + lcol], &As[row * 64]);
      gload16(&W[(size_t)(n0 + row + lrow) * K + kt + lcol], &Bs[row * 64]);
    }
    __syncthreads();
#pragma unroll
    for (int kc = 0; kc < 2; ++kc) {
      const int ko = kc * 32 + quad * 8;
      bf16x8 a[4], b[4];
#pragma unroll
      for (int mi = 0; mi < 4; ++mi)
        a[mi] = *(const bf16x8*)&As[(wr * 64 + mi * 16 + r) * 64 + ko];
#pragma unroll
      for (int ni = 0; ni < 4; ++ni)
        b[ni] = *(const bf16x8*)&Bs[(wc * 64 + ni * 16 + r) * 64 + ko];
#pragma unroll
      for (int mi = 0; mi < 4; ++mi)
#pragma unroll
        for (int ni = 0; ni < 4; ++ni)
          acc[mi][ni] = __builtin_amdgcn_mfma_f32_16x16x32_bf16(a[mi], b[ni], acc[mi][ni], 0, 0, 0);
    }
    __syncthreads();
  }

#pragma unroll
  for (int mi = 0; mi < 4; ++mi)
#pragma unroll
    for (int ni = 0; ni < 4; ++ni) {
      const int gc = n0 + wc * 64 + ni * 16 + r;
#pragma unroll
      for (int j = 0; j < 4; ++j) {
        const int gr = m0 + wr * 64 + mi * 16 + quad * 4 + j;
        Y[(size_t)gr * N + gc] = acc[mi][ni][j];
      }
    }
}

// ---------------- MFMA flash attention, swapped-QK 32x32x16, in-register P ----------------
// s = mfma(K,Q): lane (hi=lane>>5, c=lane&31) holds P[key][query=c] for its half's
// keys; softmax is lane-local. P -> PV A-operand via 16 cvt_pk + 8 permlane32_swap
// (no P LDS round-trip). V arrives slot-permuted so the PV B-frag is a straight
// ds_read_b128. Double-buffered K/V -> ONE barrier per tile. LDS = 36 KB.
// grid=(B*H, T/128): all qt-blocks of one head land on one XCD -> K/V L2-resident.
__global__ __launch_bounds__(256) void flash_mfma(const u16* __restrict__ Qb,
                                                  const u16* __restrict__ Kb,
                                                  const u16* __restrict__ Vtb,
                                                  u16* __restrict__ Yb) {
  __shared__ u16 Ks[2][64][72];
  __shared__ u16 Vt[2][64][72];   // Vt[buf][d][slot]
  const int tid = threadIdx.x;
  const int lane = tid & 63;
  const int w = tid >> 6;
  const int c = lane & 31;        // QK: query col; PV: d col
  const int hi = lane >> 5;
  const int bh = blockIdx.x, qt = blockIdx.y;
  const int b = bh >> 4, h = bh & 15;
  const int srow = lane;          // K staging row (key)
  const int sd0 = w * 16;         // K staging d-offset
  const int vrow = tid >> 2;      // V staging d row 0..63
  const int vco = (tid & 3) * 16; // V staging slot offset

  // issue K/V tile-0 loads first (hide latency under Q staging)
  bf16x8 k0, k1, v0, v1;
  {
    const size_t gk = ((size_t)((b * T_ + srow) * H_ + h)) * D_ + sd0;
    k0 = *(const bf16x8*)&Kb[gk];
    k1 = *(const bf16x8*)&Kb[gk + 8];
    const size_t gv = ((size_t)(bh * 64 + vrow)) * T_ + vco;
    v0 = *(const bf16x8*)&Vtb[gv];
    v1 = *(const bf16x8*)&Vtb[gv + 8];
  }

  // stage Q tile (128 x 64) through the Ks buffers: 2 threads per row
  {
    const int row = tid >> 1, half = tid & 1;
    const size_t g = ((size_t)((b * T_ + qt * 128 + row) * H_ + h)) * D_ + half * 32;
    u16* qd = (row < 64) ? &Ks[0][row][half * 32] : &Ks[1][row - 64][half * 32];
    *(bf16x8*)&qd[0]  = *(const bf16x8*)&Qb[g];
    *(bf16x8*)&qd[8]  = *(const bf16x8*)&Qb[g + 8];
    *(bf16x8*)&qd[16] = *(const bf16x8*)&Qb[g + 16];
    *(bf16x8*)&qd[24] = *(const bf16x8*)&Qb[g + 24];
  }
  __syncthreads();
  // qf[ks]: B-frag, lane (hi,c) = Q[w*32+c][ks*16 + hi*8 .. +8]
  bf16x8 qf[4];
  {
    const int qr = w * 32 + c;
    const u16* qs = (qr < 64) ? &Ks[0][qr][0] : &Ks[1][qr - 64][0];
#pragma unroll
    for (int ks = 0; ks < 4; ++ks)
      qf[ks] = *(const bf16x8*)&qs[ks * 16 + hi * 8];
  }
  __syncthreads();

  // write tile 0 to buf 0, prefetch tile 1
  *(bf16x8*)&Ks[0][srow][sd0] = k0;
  *(bf16x8*)&Ks[0][srow][sd0 + 8] = k1;
  *(bf16x8*)&Vt[0][vrow][vco] = v0;
  *(bf16x8*)&Vt[0][vrow][vco + 8] = v1;
  {
    const size_t gk = ((size_t)((b * T_ + 64 + srow) * H_ + h)) * D_ + sd0;
    k0 = *(const bf16x8*)&Kb[gk];
    k1 = *(const bf16x8*)&Kb[gk + 8];
    const size_t gv = ((size_t)(bh * 64 + vrow)) * T_ + 64 + vco;
    v0 = *(const bf16x8*)&Vtb[gv];
    v1 = *(const bf16x8*)&Vtb[gv + 8];
  }
  __syncthreads();

  f32x16 oacc[2];
  oacc[0] = (f32x16)(0.f);
  oacc[1] = (f32x16)(0.f);
  float l_acc = 0.f;

  const int NT = T_ / 64;  // 32
  for (int t = 0; t < NT; ++t) {
    const int cur = t & 1;

    // QK^T: s[kt2] = K[kt2*32..+32] x Q  (rows=keys, cols=queries)
    f32x16 s0 = (f32x16)(0.f), s1 = (f32x16)(0.f);
#pragma unroll
    for (int ks = 0; ks < 4; ++ks) {
      bf16x8 kf0 = *(const bf16x8*)&Ks[cur][c][ks * 16 + hi * 8];
      bf16x8 kf1 = *(const bf16x8*)&Ks[cur][32 + c][ks * 16 + hi * 8];
      s0 = __builtin_amdgcn_mfma_f32_32x32x16_bf16(kf0, qf[ks], s0, 0, 0, 0);
      s1 = __builtin_amdgcn_mfma_f32_32x32x16_bf16(kf1, qf[ks], s1, 0, 0, 0);
    }

    // stage next tile into alternate buffer; prefetch tile t+2
    if (t + 1 < NT) {
      const int nxt = cur ^ 1;
      *(bf16x8*)&Ks[nxt][srow][sd0] = k0;
      *(bf16x8*)&Ks[nxt][srow][sd0 + 8] = k1;
      *(bf16x8*)&Vt[nxt][vrow][vco] = v0;
      *(bf16x8*)&Vt[nxt][vrow][vco + 8] = v1;
      if (t + 2 < NT) {
        const size_t gk = ((size_t)((b * T_ + (t + 2) * 64 + srow) * H_ + h)) * D_ + sd0;
        k0 = *(const bf16x8*)&Kb[gk];
        k1 = *(const bf16x8*)&Kb[gk + 8];
        const size_t gv = ((size_t)(bh * 64 + vrow)) * T_ + (t + 2) * 64 + vco;
        v0 = *(const bf16x8*)&Vtb[gv];
        v1 = *(const bf16x8*)&Vtb[gv + 8];
      }
    }

    // softmax: p = exp2(s) (scale+log2e folded into Q); pack pairs; swap halves.
    // word[kt2][m][p] = keys {32kt2 + 8m + 4hi + 2p, +1} for query c.
    u32 wrd[2][4][2];
#pragma unroll
    for (int m = 0; m < 4; ++m)
#pragma unroll
      for (int p = 0; p < 2; ++p) {
        float a0 = __builtin_amdgcn_exp2f(s0[m * 4 + p * 2]);
        float a1 = __builtin_amdgcn_exp2f(s0[m * 4 + p * 2 + 1]);
        float b0 = __builtin_amdgcn_exp2f(s1[m * 4 + p * 2]);
        float b1 = __builtin_amdgcn_exp2f(s1[m * 4 + p * 2 + 1]);
        l_acc += (a0 + a1) + (b0 + b1);
        asm("v_cvt_pk_bf16_f32 %0, %1, %2" : "=v"(wrd[0][m][p]) : "v"(a0), "v"(a1));
        asm("v_cvt_pk_bf16_f32 %0, %1, %2" : "=v"(wrd[1][m][p]) : "v"(b0), "v"(b1));
      }
    // swap: wrd[kt][m][0] -> {lo:keys 8m+0,1 | hi:keys 8m+2,3},
    //       wrd[kt][m][1] -> {lo:keys 8m+4,5 | hi:keys 8m+6,7}  (query preserved)
#pragma unroll
    for (int kt2 = 0; kt2 < 2; ++kt2)
#pragma unroll
      for (int m = 0; m < 4; ++m)
        asm("v_permlane32_swap_b32 %0, %1" : "+v"(wrd[kt2][m][0]), "+v"(wrd[kt2][m][1]));

    bf16x8 pa[4];
    pa[0] = __builtin_bit_cast(bf16x8, (u32x4){wrd[0][0][0], wrd[0][0][1], wrd[0][1][0], wrd[0][1][1]});
    pa[1] = __builtin_bit_cast(bf16x8, (u32x4){wrd[0][2][0], wrd[0][2][1], wrd[0][3][0], wrd[0][3][1]});
    pa[2] = __builtin_bit_cast(bf16x8, (u32x4){wrd[1][0][0], wrd[1][0][1], wrd[1][1][0], wrd[1][1][1]});
    pa[3] = __builtin_bit_cast(bf16x8, (u32x4){wrd[1][2][0], wrd[1][2][1], wrd[1][3][0], wrd[1][3][1]});

    // O += P @ V: A=pa (rows=queries, k=keys in slot order), B=Vt slots (b128)
#pragma unroll
    for (int ks = 0; ks < 4; ++ks) {
      bf16x8 vf0 = *(const bf16x8*)&Vt[cur][c][ks * 16 + hi * 8];
      bf16x8 vf1 = *(const bf16x8*)&Vt[cur][32 + c][ks * 16 + hi * 8];
      oacc[0] = __builtin_amdgcn_mfma_f32_32x32x16_bf16(pa[ks], vf0, oacc[0], 0, 0, 0);
      oacc[1] = __builtin_amdgcn_mfma_f32_32x32x16_bf16(pa[ks], vf1, oacc[1], 0, 0, 0);
    }
    __syncthreads();
  }

  // epilogue: l total per query c, redistribute to O-row holders, scale, store
  float l_all = l_acc + __shfl_xor(l_acc, 32, 64);
#pragma unroll
  for (int v = 0; v < 16; ++v) {
    const int q = (v & 3) + 8 * (v >> 2) + 4 * hi;
    const float inv = 1.0f / __shfl(l_all, q, 64);
    const int tq = qt * 128 + w * 32 + q;
    const size_t gbase = ((size_t)((b * T_ + tq) * H_ + h)) * D_;
    Yb[gbase + c]      = f2bf(oacc[0][v] * inv);
    Yb[gbase + 32 + c] = f2bf(oacc[1][v] * inv);
  }
}

extern "C" void kernel_launch(void* const* d_in, const int* in_sizes, int n_in,
                              void* d_out, int out_size, void* d_ws, size_t ws_size,
                              hipStream_t stream) {
  const float* x    = (const float*)d_in[0];
  const float* cosb = (const float*)d_in[1];
  const float* sinb = (const float*)d_in[2];
  const float* Wq   = (const float*)d_in[3];
  const float* Wk   = (const float*)d_in[4];
  const float* Wv   = (const float*)d_in[5];
  const float* Wo   = (const float*)d_in[6];
  float* out = (float*)d_out;

  const size_t NE = (size_t)B_ * T_ * C_;  // 8M elements
  const int CC = C_ * C_;                  // 1M elements
  // workspace (~72 MB): xb,qb,kb,vtb bf16 (64 MB) + wqkv (6 MB) + wob (2 MB)
  u16* xb   = (u16*)d_ws;
  u16* qb   = xb + NE;
  u16* kb   = qb + NE;
  u16* vtb  = kb + NE;   // V transposed + slot-permuted: [(b*H+h)*D + d][T]
  u16* wqkv = vtb + NE;
  u16* wob  = wqkv + 3 * (size_t)CC;
  u16* yb   = xb;  // xb dead after QKV GEMM; reuse for attention output

  const int M = B_ * T_;  // 8192

  cvt_bf16<<<(int)(NE / 1024), 256, 0, stream>>>(x, xb, (int)NE);
  dim3 wg(CC / 1024, 4);
  cvt_weights<<<wg, 256, 0, stream>>>(Wq, Wk, Wv, Wo, wqkv, wob, CC);

  dim3 qg(24, M / 128), gb(256);
  gemm_qkv<<<qg, gb, 0, stream>>>(xb, wqkv, qb, kb, vtb, cosb, sinb, M, C_);

  dim3 fg(B_ * H_, T_ / 128);
  flash_mfma<<<fg, 256, 0, stream>>>(qb, kb, vtb, yb);

  dim3 og(C_ / 128, M / 128);
  gemm_out<<<og, gb, 0, stream>>>(yb, wob, out, M, C_, C_);
}

// Round 4
// 311.065 us; speedup vs baseline: 1.0059x; 1.0059x over previous
//
#include <hip/hip_runtime.h>

#define B_ 4
#define T_ 2048
#define C_ 1024
#define H_ 16
#define D_ 64
#define EPS_ 1.1920929e-07f
#define LOG2E_ 1.4426950408889634f

typedef __attribute__((ext_vector_type(8))) short bf16x8;
typedef __attribute__((ext_vector_type(4))) float f32x4;
typedef __attribute__((ext_vector_type(16))) float f32x16;
typedef unsigned short u16;
typedef unsigned int u32;
typedef __attribute__((ext_vector_type(4))) u32 u32x4;

__device__ inline u16 f2bf(float f) {
  unsigned u = __float_as_uint(f);
  unsigned r = (u + 0x7fffu + ((u >> 16) & 1u)) >> 16;
  return (u16)r;
}

// async global->LDS, 16B per lane (dest = wave-uniform base + lane*16)
__device__ __forceinline__ void gload16(const void* g, void* l) {
  __builtin_amdgcn_global_load_lds(
      (__attribute__((address_space(1))) void*)g,
      (__attribute__((address_space(3))) void*)l, 16, 0, 0);
}

// ---------------- all f32->bf16 conversions in ONE launch ----------------
// blocks [0, NXB): x -> xb ; blocks [NXB, NXB+4*WB): the 4 weights.
__global__ __launch_bounds__(256) void cvt_all(const float* __restrict__ x,
                                               const float* __restrict__ wq,
                                               const float* __restrict__ wk,
                                               const float* __restrict__ wv,
                                               const float* __restrict__ wo,
                                               u16* __restrict__ xb,
                                               u16* __restrict__ wqkv,
                                               u16* __restrict__ wob) {
  const int NXB = (int)((size_t)B_ * T_ * C_ / 1024);  // 8192
  const int WB = (C_ * C_) / 1024;                     // 1024
  const int bid = blockIdx.x;
  const float* src;
  u16* dst;
  int i;
  if (bid < NXB) {
    src = x; dst = xb; i = bid * 1024 + threadIdx.x * 4;
  } else {
    const int wb = bid - NXB;
    const int t = wb / WB;
    const int r = wb - t * WB;
    src = (t == 0) ? wq : (t == 1) ? wk : (t == 2) ? wv : wo;
    dst = (t == 3) ? wob : (wqkv + (size_t)t * (C_ * C_));
    i = r * 1024 + threadIdx.x * 4;
  }
  float4 v = *(const float4*)&src[i];
  ushort4 o;
  o.x = f2bf(v.x); o.y = f2bf(v.y); o.z = f2bf(v.z); o.w = f2bf(v.w);
  *(ushort4*)&dst[i] = o;
}

// ---------------- fused QKV GEMM: [Q|K|V] = X @ Wqkv^T + epilogues ----------------
// XCD swizzle: 8 consecutive m-panels per XCD -> X slice (2 MB) L2-resident.
// bx: 0..7 -> Q (rope+rms, *scale*log2e), 8..15 -> K (rope+rms),
// 16..23 -> V stored transposed + SLOT-permuted (matches flash's permlane pack).
__global__ __launch_bounds__(256) void gemm_qkv(const u16* __restrict__ X,
                                                const u16* __restrict__ W,
                                                u16* __restrict__ qb,
                                                u16* __restrict__ kb,
                                                u16* __restrict__ vtb,
                                                const float* __restrict__ cs,
                                                const float* __restrict__ sn,
                                                int M, int K) {
  __shared__ short As[128 * 64];
  __shared__ short Bs[128 * 64];
  const int tid = threadIdx.x;
  const int lane = tid & 63;
  const int w = tid >> 6;
  const int wr = w >> 1, wc = w & 1;
  // XCD-aware remap: hwlin%8 = XCD; give each XCD a contiguous chunk of
  // m-major order (grid 24 x 64 = 1536, 1536%8==0 -> bijective).
  const int hwlin = blockIdx.x + 24 * blockIdx.y;
  const int lg = (hwlin & 7) * 192 + (hwlin >> 3);
  const int bx = lg % 24, by = lg / 24;
  const int m0 = by * 128, n0 = bx * 128;
  const int lrow = lane >> 3;       // 0..7 within an 8-row chunk
  const int lcol = (lane & 7) * 8;  // u16 col within a 64-col row

  f32x4 acc[4][4];
#pragma unroll
  for (int mi = 0; mi < 4; ++mi)
#pragma unroll
    for (int ni = 0; ni < 4; ++ni)
      acc[mi][ni] = (f32x4){0.f, 0.f, 0.f, 0.f};

  const int r = lane & 15;
  const int quad = lane >> 4;

  for (int kt = 0; kt < K; kt += 64) {
#pragma unroll
    for (int i = 0; i < 4; ++i) {
      const int row = w * 32 + i * 8;  // wave-uniform LDS dest row
      gload16(&X[(size_t)(m0 + row + lrow) * K + kt + lcol], &As[row * 64]);
      gload16(&W[(size_t)(n0 + row + lrow) * K + kt + lcol], &Bs[row * 64]);
    }
    __syncthreads();
#pragma unroll
    for (int kc = 0; kc < 2; ++kc) {
      const int ko = kc * 32 + quad * 8;
      bf16x8 a[4], b[4];
#pragma unroll
      for (int mi = 0; mi < 4; ++mi)
        a[mi] = *(const bf16x8*)&As[(wr * 64 + mi * 16 + r) * 64 + ko];
#pragma unroll
      for (int ni = 0; ni < 4; ++ni)
        b[ni] = *(const bf16x8*)&Bs[(wc * 64 + ni * 16 + r) * 64 + ko];
#pragma unroll
      for (int mi = 0; mi < 4; ++mi)
#pragma unroll
        for (int ni = 0; ni < 4; ++ni)
          acc[mi][ni] = __builtin_amdgcn_mfma_f32_16x16x32_bf16(a[mi], b[ni], acc[mi][ni], 0, 0, 0);
    }
    __syncthreads();
  }

  const int which = bx >> 3;                // 0=Q 1=K 2=V
  const int c0 = (bx & 7) * 128 + wc * 64;  // column within tensor (one head/wave)

  if (which < 2) {
    u16* dst = (which == 0) ? qb : kb;
    // fused RoPE + RMSNorm; d = ni*16+r, pair (d,d+32) = (ni,ni+2) in-lane
#pragma unroll
    for (int mi = 0; mi < 4; ++mi)
#pragma unroll
      for (int j = 0; j < 4; ++j) {
        const int gr = m0 + wr * 64 + mi * 16 + quad * 4 + j;
        const int t = gr & (T_ - 1);
        float o[4];
#pragma unroll
        for (int ni = 0; ni < 2; ++ni) {
          const float c = cs[t * 32 + ni * 16 + r];
          const float s = sn[t * 32 + ni * 16 + r];
          const float x1 = acc[mi][ni][j], x2 = acc[mi][ni + 2][j];
          o[ni]     = x1 * c + x2 * s;
          o[ni + 2] = x2 * c - x1 * s;
        }
        float sq = o[0] * o[0] + o[1] * o[1] + o[2] * o[2] + o[3] * o[3];
        sq += __shfl_xor(sq, 1, 64);
        sq += __shfl_xor(sq, 2, 64);
        sq += __shfl_xor(sq, 4, 64);
        sq += __shfl_xor(sq, 8, 64);
        float rn = rsqrtf(sq * (1.0f / 64.0f) + EPS_);
        if (which == 0) rn *= 0.125f * LOG2E_;  // fold attn scale AND log2(e) into Q
#pragma unroll
        for (int ni = 0; ni < 4; ++ni)
          dst[(size_t)gr * C_ + c0 + ni * 16 + r] = f2bf(o[ni] * rn);
      }
  } else {
    // V: transposed + slot-permuted store. head h, d = ni*16+r.
    // key-in-tile = mi*16 + quad*4 + j -> slot = mi*16 + (j>>1)*8 + quad*2 + (j&1)
    const int h = (bx & 7) * 2 + wc;
    const int gr0 = m0 + wr * 64;
    const int bb = gr0 >> 11;         // batch (T_=2048)
    const int tbase = gr0 & (T_ - 1); // multiple of 64
#pragma unroll
    for (int ni = 0; ni < 4; ++ni) {
      const int d = ni * 16 + r;
      u16* rowp = &vtb[((size_t)((bb * H_ + h) * D_ + d)) * T_ + tbase];
#pragma unroll
      for (int mi = 0; mi < 4; ++mi) {
        u32 lo, hi2;
        asm("v_cvt_pk_bf16_f32 %0, %1, %2" : "=v"(lo) : "v"(acc[mi][ni][0]), "v"(acc[mi][ni][1]));
        asm("v_cvt_pk_bf16_f32 %0, %1, %2" : "=v"(hi2) : "v"(acc[mi][ni][2]), "v"(acc[mi][ni][3]));
        u16* p = rowp + mi * 16 + quad * 2;
        *(u32*)&p[0] = lo;
        *(u32*)&p[8] = hi2;
      }
    }
  }
}

// ---------------- output GEMM: out = Y @ Wo^T (fp32 out) ----------------
__global__ __launch_bounds__(256) void gemm_out(const u16* __restrict__ X,
                                                const u16* __restrict__ W,
                                                float* __restrict__ Y,
                                                int M, int N, int K) {
  __shared__ short As[128 * 64];
  __shared__ short Bs[128 * 64];
  const int tid = threadIdx.x;
  const int lane = tid & 63;
  const int w = tid >> 6;
  const int wr = w >> 1, wc = w & 1;
  // XCD swizzle (grid 8 x 64 = 512, 512%8==0): 8 m-panels per XCD ->
  // X slice 2 MB + Wo 2 MB = L2-resident per XCD.
  const int hwlin = blockIdx.x + 8 * blockIdx.y;
  const int lg = (hwlin & 7) * 64 + (hwlin >> 3);
  const int bx = lg & 7, by = lg >> 3;
  const int m0 = by * 128, n0 = bx * 128;
  const int lrow = lane >> 3;
  const int lcol = (lane & 7) * 8;

  f32x4 acc[4][4];
#pragma unroll
  for (int mi = 0; mi < 4; ++mi)
#pragma unroll
    for (int ni = 0; ni < 4; ++ni)
      acc[mi][ni] = (f32x4){0.f, 0.f, 0.f, 0.f};

  const int r = lane & 15;
  const int quad = lane >> 4;

  for (int kt = 0; kt < K; kt += 64) {
#pragma unroll
    for (int i = 0; i < 4; ++i) {
      const int row = w * 32 + i * 8;
      gload16(&X[(size_t)(m0 + row + lrow) * K + kt + lcol], &As[row * 64]);
      gload16(&W[(size_t)(n0 + row + lrow) * K + kt + lcol], &Bs[row * 64]);
    }
    __syncthreads();
#pragma unroll
    for (int kc = 0; kc < 2; ++kc) {
      const int ko = kc * 32 + quad * 8;
      bf16x8 a[4], b[4];
#pragma unroll
      for (int mi = 0; mi < 4; ++mi)
        a[mi] = *(const bf16x8*)&As[(wr * 64 + mi * 16 + r) * 64 + ko];
#pragma unroll
      for (int ni = 0; ni < 4; ++ni)
        b[ni] = *(const bf16x8*)&Bs[(wc * 64 + ni * 16 + r) * 64 + ko];
#pragma unroll
      for (int mi = 0; mi < 4; ++mi)
#pragma unroll
        for (int ni = 0; ni < 4; ++ni)
          acc[mi][ni] = __builtin_amdgcn_mfma_f32_16x16x32_bf16(a[mi], b[ni], acc[mi][ni], 0, 0, 0);
    }
    __syncthreads();
  }

#pragma unroll
  for (int mi = 0; mi < 4; ++mi)
#pragma unroll
    for (int ni = 0; ni < 4; ++ni) {
      const int gc = n0 + wc * 64 + ni * 16 + r;
#pragma unroll
      for (int j = 0; j < 4; ++j) {
        const int gr = m0 + wr * 64 + mi * 16 + quad * 4 + j;
        Y[(size_t)gr * N + gc] = acc[mi][ni][j];
      }
    }
}

// ---------------- MFMA flash attention, swapped-QK 32x32x16, in-register P ----------------
// s = mfma(K,Q): lane (hi,c) holds P[key][query=c]; softmax lane-local.
// P -> PV A-operand via 16 cvt_pk + 8 permlane32_swap (no LDS round-trip).
// l accumulated by a ones-column MFMA: oacc_l[v] lands on exactly the lane/reg
// of oacc[*][v]'s row -> epilogue has ZERO shuffles. Double-buffered K/V,
// one barrier/tile; unroll-2 makes all buffer offsets compile-time.
__global__ __launch_bounds__(256) void flash_mfma(const u16* __restrict__ Qb,
                                                  const u16* __restrict__ Kb,
                                                  const u16* __restrict__ Vtb,
                                                  u16* __restrict__ Yb) {
  __shared__ u16 Ks[2][64][72];
  __shared__ u16 Vt[2][64][72];   // Vt[buf][d][slot]
  const int tid = threadIdx.x;
  const int lane = tid & 63;
  const int w = tid >> 6;
  const int c = lane & 31;        // QK: query col; PV: d col
  const int hi = lane >> 5;
  const int bh = blockIdx.x, qt = blockIdx.y;
  const int b = bh >> 4, h = bh & 15;
  const int srow = lane;          // K staging row (key)
  const int sd0 = w * 16;         // K staging d-offset
  const int vrow = tid >> 2;      // V staging d row 0..63
  const int vco = (tid & 3) * 16; // V staging slot offset

  const u16* kbase = Kb + ((size_t)(b * T_ + srow) * H_ + h) * D_ + sd0;
  const u16* vbase = Vtb + ((size_t)(bh * 64 + vrow)) * T_ + vco;
  const int KSTRIDE = 64 * H_ * D_;  // u16 elems per 64-key tile

  // issue K/V tile-0 loads first (hide latency under Q staging)
  bf16x8 k0, k1, v0, v1;
  k0 = *(const bf16x8*)&kbase[0];
  k1 = *(const bf16x8*)&kbase[8];
  v0 = *(const bf16x8*)&vbase[0];
  v1 = *(const bf16x8*)&vbase[8];

  // stage Q tile (128 x 64) through the Ks buffers: 2 threads per row
  {
    const int row = tid >> 1, half = tid & 1;
    const size_t g = ((size_t)((b * T_ + qt * 128 + row) * H_ + h)) * D_ + half * 32;
    u16* qd = (row < 64) ? &Ks[0][row][half * 32] : &Ks[1][row - 64][half * 32];
    *(bf16x8*)&qd[0]  = *(const bf16x8*)&Qb[g];
    *(bf16x8*)&qd[8]  = *(const bf16x8*)&Qb[g + 8];
    *(bf16x8*)&qd[16] = *(const bf16x8*)&Qb[g + 16];
    *(bf16x8*)&qd[24] = *(const bf16x8*)&Qb[g + 24];
  }
  __syncthreads();
  // qf[ks]: B-frag, lane (hi,c) = Q[w*32+c][ks*16 + hi*8 .. +8]
  bf16x8 qf[4];
  {
    const int qr = w * 32 + c;
    const u16* qs = (qr < 64) ? &Ks[0][qr][0] : &Ks[1][qr - 64][0];
#pragma unroll
    for (int ks = 0; ks < 4; ++ks)
      qf[ks] = *(const bf16x8*)&qs[ks * 16 + hi * 8];
  }
  __syncthreads();

  // write tile 0 to buf 0, prefetch tile 1
  *(bf16x8*)&Ks[0][srow][sd0] = k0;
  *(bf16x8*)&Ks[0][srow][sd0 + 8] = k1;
  *(bf16x8*)&Vt[0][vrow][vco] = v0;
  *(bf16x8*)&Vt[0][vrow][vco + 8] = v1;
  k0 = *(const bf16x8*)&kbase[KSTRIDE];
  k1 = *(const bf16x8*)&kbase[KSTRIDE + 8];
  v0 = *(const bf16x8*)&vbase[64];
  v1 = *(const bf16x8*)&vbase[64 + 8];
  __syncthreads();

  f32x16 oacc[2], oacc_l;
  oacc[0] = (f32x16)(0.f);
  oacc[1] = (f32x16)(0.f);
  oacc_l  = (f32x16)(0.f);
  bf16x8 onesv;
#pragma unroll
  for (int i = 0; i < 8; ++i) onesv[i] = (short)0x3F80;  // bf16 1.0

  const int NT = T_ / 64;  // 32
#pragma unroll 2
  for (int t = 0; t < NT; ++t) {
    const int cur = t & 1;

    // QK^T: s[kt2] = K[kt2*32..+32] x Q  (rows=keys, cols=queries)
    f32x16 s0 = (f32x16)(0.f), s1 = (f32x16)(0.f);
    __builtin_amdgcn_s_setprio(1);
#pragma unroll
    for (int ks = 0; ks < 4; ++ks) {
      bf16x8 kf0 = *(const bf16x8*)&Ks[cur][c][ks * 16 + hi * 8];
      bf16x8 kf1 = *(const bf16x8*)&Ks[cur][32 + c][ks * 16 + hi * 8];
      s0 = __builtin_amdgcn_mfma_f32_32x32x16_bf16(kf0, qf[ks], s0, 0, 0, 0);
      s1 = __builtin_amdgcn_mfma_f32_32x32x16_bf16(kf1, qf[ks], s1, 0, 0, 0);
    }
    __builtin_amdgcn_s_setprio(0);

    // stage next tile into alternate buffer; prefetch tile t+2
    if (t + 1 < NT) {
      const int nxt = cur ^ 1;
      *(bf16x8*)&Ks[nxt][srow][sd0] = k0;
      *(bf16x8*)&Ks[nxt][srow][sd0 + 8] = k1;
      *(bf16x8*)&Vt[nxt][vrow][vco] = v0;
      *(bf16x8*)&Vt[nxt][vrow][vco + 8] = v1;
      if (t + 2 < NT) {
        const int gk = (t + 2) * KSTRIDE;
        k0 = *(const bf16x8*)&kbase[gk];
        k1 = *(const bf16x8*)&kbase[gk + 8];
        const int gv = (t + 2) * 64;
        v0 = *(const bf16x8*)&vbase[gv];
        v1 = *(const bf16x8*)&vbase[gv + 8];
      }
    }

    // softmax: p = exp2(s) (scale+log2e folded into Q); pack pairs; swap halves.
    u32 wrd[2][4][2];
#pragma unroll
    for (int m = 0; m < 4; ++m)
#pragma unroll
      for (int p = 0; p < 2; ++p) {
        float a0 = __builtin_amdgcn_exp2f(s0[m * 4 + p * 2]);
        float a1 = __builtin_amdgcn_exp2f(s0[m * 4 + p * 2 + 1]);
        float b0 = __builtin_amdgcn_exp2f(s1[m * 4 + p * 2]);
        float b1 = __builtin_amdgcn_exp2f(s1[m * 4 + p * 2 + 1]);
        asm("v_cvt_pk_bf16_f32 %0, %1, %2" : "=v"(wrd[0][m][p]) : "v"(a0), "v"(a1));
        asm("v_cvt_pk_bf16_f32 %0, %1, %2" : "=v"(wrd[1][m][p]) : "v"(b0), "v"(b1));
      }
#pragma unroll
    for (int kt2 = 0; kt2 < 2; ++kt2)
#pragma unroll
      for (int m = 0; m < 4; ++m)
        asm("v_permlane32_swap_b32 %0, %1" : "+v"(wrd[kt2][m][0]), "+v"(wrd[kt2][m][1]));

    bf16x8 pa[4];
    pa[0] = __builtin_bit_cast(bf16x8, (u32x4){wrd[0][0][0], wrd[0][0][1], wrd[0][1][0], wrd[0][1][1]});
    pa[1] = __builtin_bit_cast(bf16x8, (u32x4){wrd[0][2][0], wrd[0][2][1], wrd[0][3][0], wrd[0][3][1]});
    pa[2] = __builtin_bit_cast(bf16x8, (u32x4){wrd[1][0][0], wrd[1][0][1], wrd[1][1][0], wrd[1][1][1]});
    pa[3] = __builtin_bit_cast(bf16x8, (u32x4){wrd[1][2][0], wrd[1][2][1], wrd[1][3][0], wrd[1][3][1]});

    // O += P @ V ; l += P @ ones (row-sum lands aligned with oacc rows)
    __builtin_amdgcn_s_setprio(1);
#pragma unroll
    for (int ks = 0; ks < 4; ++ks) {
      bf16x8 vf0 = *(const bf16x8*)&Vt[cur][c][ks * 16 + hi * 8];
      bf16x8 vf1 = *(const bf16x8*)&Vt[cur][32 + c][ks * 16 + hi * 8];
      oacc[0] = __builtin_amdgcn_mfma_f32_32x32x16_bf16(pa[ks], vf0, oacc[0], 0, 0, 0);
      oacc[1] = __builtin_amdgcn_mfma_f32_32x32x16_bf16(pa[ks], vf1, oacc[1], 0, 0, 0);
      oacc_l  = __builtin_amdgcn_mfma_f32_32x32x16_bf16(pa[ks], onesv, oacc_l, 0, 0, 0);
    }
    __builtin_amdgcn_s_setprio(0);
    __syncthreads();
  }

  // epilogue: inv = 1/l, perfectly aligned with O rows -- no shuffles
#pragma unroll
  for (int v = 0; v < 16; ++v) {
    const float inv = 1.0f / oacc_l[v];
    const int q = (v & 3) + 8 * (v >> 2) + 4 * hi;
    const int tq = qt * 128 + w * 32 + q;
    const size_t gbase = ((size_t)((b * T_ + tq) * H_ + h)) * D_;
    Yb[gbase + c]      = f2bf(oacc[0][v] * inv);
    Yb[gbase + 32 + c] = f2bf(oacc[1][v] * inv);
  }
}

extern "C" void kernel_launch(void* const* d_in, const int* in_sizes, int n_in,
                              void* d_out, int out_size, void* d_ws, size_t ws_size,
                              hipStream_t stream) {
  const float* x    = (const float*)d_in[0];
  const float* cosb = (const float*)d_in[1];
  const float* sinb = (const float*)d_in[2];
  const float* Wq   = (const float*)d_in[3];
  const float* Wk   = (const float*)d_in[4];
  const float* Wv   = (const float*)d_in[5];
  const float* Wo   = (const float*)d_in[6];
  float* out = (float*)d_out;

  const size_t NE = (size_t)B_ * T_ * C_;  // 8M elements
  const int CC = C_ * C_;                  // 1M elements
  // workspace (~72 MB): xb,qb,kb,vtb bf16 (64 MB) + wqkv (6 MB) + wob (2 MB)
  u16* xb   = (u16*)d_ws;
  u16* qb   = xb + NE;
  u16* kb   = qb + NE;
  u16* vtb  = kb + NE;   // V transposed + slot-permuted: [(b*H+h)*D + d][T]
  u16* wqkv = vtb + NE;
  u16* wob  = wqkv + 3 * (size_t)CC;
  u16* yb   = xb;  // xb dead after QKV GEMM; reuse for attention output

  const int M = B_ * T_;  // 8192

  const int NXB = (int)(NE / 1024);          // 8192
  const int NWB = 4 * (CC / 1024);           // 4096
  cvt_all<<<NXB + NWB, 256, 0, stream>>>(x, Wq, Wk, Wv, Wo, xb, wqkv, wob);

  dim3 qg(24, M / 128), gb(256);
  gemm_qkv<<<qg, gb, 0, stream>>>(xb, wqkv, qb, kb, vtb, cosb, sinb, M, C_);

  dim3 fg(B_ * H_, T_ / 128);
  flash_mfma<<<fg, 256, 0, stream>>>(qb, kb, vtb, yb);

  dim3 og(C_ / 128, M / 128);
  gemm_out<<<og, gb, 0, stream>>>(yb, wob, out, M, C_, C_);
}

// Round 5
// 309.024 us; speedup vs baseline: 1.0125x; 1.0066x over previous
//
#include <hip/hip_runtime.h>

#define B_ 4
#define T_ 2048
#define C_ 1024
#define H_ 16
#define D_ 64
#define EPS_ 1.1920929e-07f
#define LOG2E_ 1.4426950408889634f

typedef __attribute__((ext_vector_type(8))) short bf16x8;
typedef __attribute__((ext_vector_type(4))) float f32x4;
typedef __attribute__((ext_vector_type(16))) float f32x16;
typedef unsigned short u16;
typedef unsigned int u32;
typedef __attribute__((ext_vector_type(4))) u32 u32x4;

__device__ inline u16 f2bf(float f) {
  unsigned u = __float_as_uint(f);
  unsigned r = (u + 0x7fffu + ((u >> 16) & 1u)) >> 16;
  return (u16)r;
}

// async global->LDS, 16B per lane (dest = wave-uniform base + lane*16)
__device__ __forceinline__ void gload16(const void* g, void* l) {
  __builtin_amdgcn_global_load_lds(
      (__attribute__((address_space(1))) void*)g,
      (__attribute__((address_space(3))) void*)l, 16, 0, 0);
}

// ---------------- all f32->bf16 conversions in ONE launch ----------------
__global__ __launch_bounds__(256) void cvt_all(const float* __restrict__ x,
                                               const float* __restrict__ wq,
                                               const float* __restrict__ wk,
                                               const float* __restrict__ wv,
                                               const float* __restrict__ wo,
                                               u16* __restrict__ xb,
                                               u16* __restrict__ wqkv,
                                               u16* __restrict__ wob) {
  const int NXB = (int)((size_t)B_ * T_ * C_ / 1024);  // 8192
  const int WB = (C_ * C_) / 1024;                     // 1024
  const int bid = blockIdx.x;
  const float* src;
  u16* dst;
  int i;
  if (bid < NXB) {
    src = x; dst = xb; i = bid * 1024 + threadIdx.x * 4;
  } else {
    const int wb = bid - NXB;
    const int t = wb / WB;
    const int r = wb - t * WB;
    src = (t == 0) ? wq : (t == 1) ? wk : (t == 2) ? wv : wo;
    dst = (t == 3) ? wob : (wqkv + (size_t)t * (C_ * C_));
    i = r * 1024 + threadIdx.x * 4;
  }
  float4 v = *(const float4*)&src[i];
  ushort4 o;
  o.x = f2bf(v.x); o.y = f2bf(v.y); o.z = f2bf(v.z); o.w = f2bf(v.w);
  *(ushort4*)&dst[i] = o;
}

// ---------------- fused QKV GEMM: [Q|K|V] = X @ Wqkv^T + epilogues ----------------
// 128x256 tile, BK=64, 8 waves (2M x 4N, per-wave 64x64), double-buffered LDS,
// ONE barrier per K-step: STAGE(next) issued before MFMA(cur), __syncthreads
// drains vmcnt -> next buffer ready. Grid 12x64 = 768 blocks = exactly 3/CU.
// bx: 0..3 -> Q (rope+rms, *scale*log2e), 4..7 -> K (rope+rms),
// 8..11 -> V stored transposed + SLOT-permuted (matches flash's permlane pack).
__global__ __launch_bounds__(512) void gemm_qkv(const u16* __restrict__ X,
                                                const u16* __restrict__ W,
                                                u16* __restrict__ qb,
                                                u16* __restrict__ kb,
                                                u16* __restrict__ vtb,
                                                const float* __restrict__ cs,
                                                const float* __restrict__ sn,
                                                int M, int K) {
  __shared__ short As[2][128 * 64];
  __shared__ short Bs[2][256 * 64];
  const int tid = threadIdx.x;
  const int lane = tid & 63;
  const int wid = tid >> 6;           // 0..7
  const int wm = wid >> 2, wn = wid & 3;
  const int bx = blockIdx.x, by = blockIdx.y;
  const int m0 = by * 128, n0 = bx * 256;
  const int w8 = wid * 8;
  const int lrow = lane >> 3;         // 0..7
  const int lcol = (lane & 7) * 8;    // u16 col within 64-col row

  f32x4 acc[4][4];
#pragma unroll
  for (int mi = 0; mi < 4; ++mi)
#pragma unroll
    for (int ni = 0; ni < 4; ++ni)
      acc[mi][ni] = (f32x4){0.f, 0.f, 0.f, 0.f};

  const int r = lane & 15;
  const int quad = lane >> 4;

  // prologue: stage tile 0 into buf 0
#pragma unroll
  for (int ra = 0; ra < 2; ++ra)
    gload16(&X[(size_t)(m0 + ra * 64 + w8 + lrow) * K + lcol], &As[0][(ra * 64 + w8) * 64]);
#pragma unroll
  for (int rb = 0; rb < 4; ++rb)
    gload16(&W[(size_t)(n0 + rb * 64 + w8 + lrow) * K + lcol], &Bs[0][(rb * 64 + w8) * 64]);
  __syncthreads();

#pragma unroll 2
  for (int it = 0; it < 16; ++it) {   // K = 1024 = 16 * 64
    const int cur = it & 1;
    const int kt = it * 64;
    if (it + 1 < 16) {                // stage next tile into alternate buffer
      const int nb = cur ^ 1;
#pragma unroll
      for (int ra = 0; ra < 2; ++ra)
        gload16(&X[(size_t)(m0 + ra * 64 + w8 + lrow) * K + kt + 64 + lcol], &As[nb][(ra * 64 + w8) * 64]);
#pragma unroll
      for (int rb = 0; rb < 4; ++rb)
        gload16(&W[(size_t)(n0 + rb * 64 + w8 + lrow) * K + kt + 64 + lcol], &Bs[nb][(rb * 64 + w8) * 64]);
    }
#pragma unroll
    for (int kc = 0; kc < 2; ++kc) {
      const int ko = kc * 32 + quad * 8;
      bf16x8 a[4], b[4];
#pragma unroll
      for (int mi = 0; mi < 4; ++mi)
        a[mi] = *(const bf16x8*)&As[cur][(wm * 64 + mi * 16 + r) * 64 + ko];
#pragma unroll
      for (int ni = 0; ni < 4; ++ni)
        b[ni] = *(const bf16x8*)&Bs[cur][(wn * 64 + ni * 16 + r) * 64 + ko];
#pragma unroll
      for (int mi = 0; mi < 4; ++mi)
#pragma unroll
        for (int ni = 0; ni < 4; ++ni)
          acc[mi][ni] = __builtin_amdgcn_mfma_f32_16x16x32_bf16(a[mi], b[ni], acc[mi][ni], 0, 0, 0);
    }
    __syncthreads();                  // drains vmcnt -> staged tile visible
  }

  const int which = bx >> 2;                 // 0=Q 1=K 2=V
  const int c0 = (bx & 3) * 256 + wn * 64;   // column within tensor (one head/wave)

  if (which < 2) {
    u16* dst = (which == 0) ? qb : kb;
    // fused RoPE + RMSNorm; d = ni*16+r, pair (d,d+32) = (ni,ni+2) in-lane
#pragma unroll
    for (int mi = 0; mi < 4; ++mi)
#pragma unroll
      for (int j = 0; j < 4; ++j) {
        const int gr = m0 + wm * 64 + mi * 16 + quad * 4 + j;
        const int t = gr & (T_ - 1);
        float o[4];
#pragma unroll
        for (int ni = 0; ni < 2; ++ni) {
          const float c = cs[t * 32 + ni * 16 + r];
          const float s = sn[t * 32 + ni * 16 + r];
          const float x1 = acc[mi][ni][j], x2 = acc[mi][ni + 2][j];
          o[ni]     = x1 * c + x2 * s;
          o[ni + 2] = x2 * c - x1 * s;
        }
        float sq = o[0] * o[0] + o[1] * o[1] + o[2] * o[2] + o[3] * o[3];
        sq += __shfl_xor(sq, 1, 64);
        sq += __shfl_xor(sq, 2, 64);
        sq += __shfl_xor(sq, 4, 64);
        sq += __shfl_xor(sq, 8, 64);
        float rn = rsqrtf(sq * (1.0f / 64.0f) + EPS_);
        if (which == 0) rn *= 0.125f * LOG2E_;  // fold attn scale AND log2(e) into Q
#pragma unroll
        for (int ni = 0; ni < 4; ++ni)
          dst[(size_t)gr * C_ + c0 + ni * 16 + r] = f2bf(o[ni] * rn);
      }
  } else {
    // V: transposed + slot-permuted store. head h, d = ni*16+r.
    // key-in-tile = mi*16 + quad*4 + j -> slot = mi*16 + (j>>1)*8 + quad*2 + (j&1)
    const int h = (bx & 3) * 4 + wn;
    const int gr0 = m0 + wm * 64;
    const int bb = gr0 >> 11;         // batch (T_=2048)
    const int tbase = gr0 & (T_ - 1); // multiple of 64
#pragma unroll
    for (int ni = 0; ni < 4; ++ni) {
      const int d = ni * 16 + r;
      u16* rowp = &vtb[((size_t)((bb * H_ + h) * D_ + d)) * T_ + tbase];
#pragma unroll
      for (int mi = 0; mi < 4; ++mi) {
        u32 lo, hi2;
        asm("v_cvt_pk_bf16_f32 %0, %1, %2" : "=v"(lo) : "v"(acc[mi][ni][0]), "v"(acc[mi][ni][1]));
        asm("v_cvt_pk_bf16_f32 %0, %1, %2" : "=v"(hi2) : "v"(acc[mi][ni][2]), "v"(acc[mi][ni][3]));
        u16* p = rowp + mi * 16 + quad * 2;
        *(u32*)&p[0] = lo;
        *(u32*)&p[8] = hi2;
      }
    }
  }
}

// ---------------- output GEMM: out = Y @ Wo^T (fp32 out) ----------------
// same 128x256 / 8-wave / single-barrier dbuf structure. Grid 4x64 = 256 = 1/CU.
__global__ __launch_bounds__(512) void gemm_out(const u16* __restrict__ X,
                                                const u16* __restrict__ W,
                                                float* __restrict__ Y,
                                                int M, int N, int K) {
  __shared__ short As[2][128 * 64];
  __shared__ short Bs[2][256 * 64];
  const int tid = threadIdx.x;
  const int lane = tid & 63;
  const int wid = tid >> 6;
  const int wm = wid >> 2, wn = wid & 3;
  const int m0 = blockIdx.y * 128, n0 = blockIdx.x * 256;
  const int w8 = wid * 8;
  const int lrow = lane >> 3;
  const int lcol = (lane & 7) * 8;

  f32x4 acc[4][4];
#pragma unroll
  for (int mi = 0; mi < 4; ++mi)
#pragma unroll
    for (int ni = 0; ni < 4; ++ni)
      acc[mi][ni] = (f32x4){0.f, 0.f, 0.f, 0.f};

  const int r = lane & 15;
  const int quad = lane >> 4;

#pragma unroll
  for (int ra = 0; ra < 2; ++ra)
    gload16(&X[(size_t)(m0 + ra * 64 + w8 + lrow) * K + lcol], &As[0][(ra * 64 + w8) * 64]);
#pragma unroll
  for (int rb = 0; rb < 4; ++rb)
    gload16(&W[(size_t)(n0 + rb * 64 + w8 + lrow) * K + lcol], &Bs[0][(rb * 64 + w8) * 64]);
  __syncthreads();

#pragma unroll 2
  for (int it = 0; it < 16; ++it) {
    const int cur = it & 1;
    const int kt = it * 64;
    if (it + 1 < 16) {
      const int nb = cur ^ 1;
#pragma unroll
      for (int ra = 0; ra < 2; ++ra)
        gload16(&X[(size_t)(m0 + ra * 64 + w8 + lrow) * K + kt + 64 + lcol], &As[nb][(ra * 64 + w8) * 64]);
#pragma unroll
      for (int rb = 0; rb < 4; ++rb)
        gload16(&W[(size_t)(n0 + rb * 64 + w8 + lrow) * K + kt + 64 + lcol], &Bs[nb][(rb * 64 + w8) * 64]);
    }
#pragma unroll
    for (int kc = 0; kc < 2; ++kc) {
      const int ko = kc * 32 + quad * 8;
      bf16x8 a[4], b[4];
#pragma unroll
      for (int mi = 0; mi < 4; ++mi)
        a[mi] = *(const bf16x8*)&As[cur][(wm * 64 + mi * 16 + r) * 64 + ko];
#pragma unroll
      for (int ni = 0; ni < 4; ++ni)
        b[ni] = *(const bf16x8*)&Bs[cur][(wn * 64 + ni * 16 + r) * 64 + ko];
#pragma unroll
      for (int mi = 0; mi < 4; ++mi)
#pragma unroll
        for (int ni = 0; ni < 4; ++ni)
          acc[mi][ni] = __builtin_amdgcn_mfma_f32_16x16x32_bf16(a[mi], b[ni], acc[mi][ni], 0, 0, 0);
    }
    __syncthreads();
  }

#pragma unroll
  for (int mi = 0; mi < 4; ++mi)
#pragma unroll
    for (int ni = 0; ni < 4; ++ni) {
      const int gc = n0 + wn * 64 + ni * 16 + r;
#pragma unroll
      for (int j = 0; j < 4; ++j) {
        const int gr = m0 + wm * 64 + mi * 16 + quad * 4 + j;
        Y[(size_t)gr * N + gc] = acc[mi][ni][j];
      }
    }
}

// ---------------- MFMA flash attention, swapped-QK 32x32x16, in-register P ----------------
// s = mfma(K,Q): lane (hi,c) holds P[key][query=c]; softmax lane-local.
// P -> PV A-operand via 16 cvt_pk + 8 permlane32_swap (no LDS round-trip).
// l accumulated by a ones-column MFMA: oacc_l[v] lands on exactly the lane/reg
// of oacc[*][v]'s row -> epilogue has ZERO shuffles. Double-buffered K/V,
// one barrier/tile; unroll-2 makes all buffer offsets compile-time.
__global__ __launch_bounds__(256) void flash_mfma(const u16* __restrict__ Qb,
                                                  const u16* __restrict__ Kb,
                                                  const u16* __restrict__ Vtb,
                                                  u16* __restrict__ Yb) {
  __shared__ u16 Ks[2][64][72];
  __shared__ u16 Vt[2][64][72];   // Vt[buf][d][slot]
  const int tid = threadIdx.x;
  const int lane = tid & 63;
  const int w = tid >> 6;
  const int c = lane & 31;        // QK: query col; PV: d col
  const int hi = lane >> 5;
  const int bh = blockIdx.x, qt = blockIdx.y;
  const int b = bh >> 4, h = bh & 15;
  const int srow = lane;          // K staging row (key)
  const int sd0 = w * 16;         // K staging d-offset
  const int vrow = tid >> 2;      // V staging d row 0..63
  const int vco = (tid & 3) * 16; // V staging slot offset

  const u16* kbase = Kb + ((size_t)(b * T_ + srow) * H_ + h) * D_ + sd0;
  const u16* vbase = Vtb + ((size_t)(bh * 64 + vrow)) * T_ + vco;
  const int KSTRIDE = 64 * H_ * D_;  // u16 elems per 64-key tile

  // issue K/V tile-0 loads first (hide latency under Q staging)
  bf16x8 k0, k1, v0, v1;
  k0 = *(const bf16x8*)&kbase[0];
  k1 = *(const bf16x8*)&kbase[8];
  v0 = *(const bf16x8*)&vbase[0];
  v1 = *(const bf16x8*)&vbase[8];

  // stage Q tile (128 x 64) through the Ks buffers: 2 threads per row
  {
    const int row = tid >> 1, half = tid & 1;
    const size_t g = ((size_t)((b * T_ + qt * 128 + row) * H_ + h)) * D_ + half * 32;
    u16* qd = (row < 64) ? &Ks[0][row][half * 32] : &Ks[1][row - 64][half * 32];
    *(bf16x8*)&qd[0]  = *(const bf16x8*)&Qb[g];
    *(bf16x8*)&qd[8]  = *(const bf16x8*)&Qb[g + 8];
    *(bf16x8*)&qd[16] = *(const bf16x8*)&Qb[g + 16];
    *(bf16x8*)&qd[24] = *(const bf16x8*)&Qb[g + 24];
  }
  __syncthreads();
  // qf[ks]: B-frag, lane (hi,c) = Q[w*32+c][ks*16 + hi*8 .. +8]
  bf16x8 qf[4];
  {
    const int qr = w * 32 + c;
    const u16* qs = (qr < 64) ? &Ks[0][qr][0] : &Ks[1][qr - 64][0];
#pragma unroll
    for (int ks = 0; ks < 4; ++ks)
      qf[ks] = *(const bf16x8*)&qs[ks * 16 + hi * 8];
  }
  __syncthreads();

  // write tile 0 to buf 0, prefetch tile 1
  *(bf16x8*)&Ks[0][srow][sd0] = k0;
  *(bf16x8*)&Ks[0][srow][sd0 + 8] = k1;
  *(bf16x8*)&Vt[0][vrow][vco] = v0;
  *(bf16x8*)&Vt[0][vrow][vco + 8] = v1;
  k0 = *(const bf16x8*)&kbase[KSTRIDE];
  k1 = *(const bf16x8*)&kbase[KSTRIDE + 8];
  v0 = *(const bf16x8*)&vbase[64];
  v1 = *(const bf16x8*)&vbase[64 + 8];
  __syncthreads();

  f32x16 oacc[2], oacc_l;
  oacc[0] = (f32x16)(0.f);
  oacc[1] = (f32x16)(0.f);
  oacc_l  = (f32x16)(0.f);
  bf16x8 onesv;
#pragma unroll
  for (int i = 0; i < 8; ++i) onesv[i] = (short)0x3F80;  // bf16 1.0

  const int NT = T_ / 64;  // 32
#pragma unroll 2
  for (int t = 0; t < NT; ++t) {
    const int cur = t & 1;

    // QK^T: s[kt2] = K[kt2*32..+32] x Q  (rows=keys, cols=queries)
    f32x16 s0 = (f32x16)(0.f), s1 = (f32x16)(0.f);
    __builtin_amdgcn_s_setprio(1);
#pragma unroll
    for (int ks = 0; ks < 4; ++ks) {
      bf16x8 kf0 = *(const bf16x8*)&Ks[cur][c][ks * 16 + hi * 8];
      bf16x8 kf1 = *(const bf16x8*)&Ks[cur][32 + c][ks * 16 + hi * 8];
      s0 = __builtin_amdgcn_mfma_f32_32x32x16_bf16(kf0, qf[ks], s0, 0, 0, 0);
      s1 = __builtin_amdgcn_mfma_f32_32x32x16_bf16(kf1, qf[ks], s1, 0, 0, 0);
    }
    __builtin_amdgcn_s_setprio(0);

    // stage next tile into alternate buffer; prefetch tile t+2
    if (t + 1 < NT) {
      const int nxt = cur ^ 1;
      *(bf16x8*)&Ks[nxt][srow][sd0] = k0;
      *(bf16x8*)&Ks[nxt][srow][sd0 + 8] = k1;
      *(bf16x8*)&Vt[nxt][vrow][vco] = v0;
      *(bf16x8*)&Vt[nxt][vrow][vco + 8] = v1;
      if (t + 2 < NT) {
        const int gk = (t + 2) * KSTRIDE;
        k0 = *(const bf16x8*)&kbase[gk];
        k1 = *(const bf16x8*)&kbase[gk + 8];
        const int gv = (t + 2) * 64;
        v0 = *(const bf16x8*)&vbase[gv];
        v1 = *(const bf16x8*)&vbase[gv + 8];
      }
    }

    // softmax: p = exp2(s) (scale+log2e folded into Q); pack pairs; swap halves.
    u32 wrd[2][4][2];
#pragma unroll
    for (int m = 0; m < 4; ++m)
#pragma unroll
      for (int p = 0; p < 2; ++p) {
        float a0 = __builtin_amdgcn_exp2f(s0[m * 4 + p * 2]);
        float a1 = __builtin_amdgcn_exp2f(s0[m * 4 + p * 2 + 1]);
        float b0 = __builtin_amdgcn_exp2f(s1[m * 4 + p * 2]);
        float b1 = __builtin_amdgcn_exp2f(s1[m * 4 + p * 2 + 1]);
        asm("v_cvt_pk_bf16_f32 %0, %1, %2" : "=v"(wrd[0][m][p]) : "v"(a0), "v"(a1));
        asm("v_cvt_pk_bf16_f32 %0, %1, %2" : "=v"(wrd[1][m][p]) : "v"(b0), "v"(b1));
      }
#pragma unroll
    for (int kt2 = 0; kt2 < 2; ++kt2)
#pragma unroll
      for (int m = 0; m < 4; ++m)
        asm("v_permlane32_swap_b32 %0, %1" : "+v"(wrd[kt2][m][0]), "+v"(wrd[kt2][m][1]));

    bf16x8 pa[4];
    pa[0] = __builtin_bit_cast(bf16x8, (u32x4){wrd[0][0][0], wrd[0][0][1], wrd[0][1][0], wrd[0][1][1]});
    pa[1] = __builtin_bit_cast(bf16x8, (u32x4){wrd[0][2][0], wrd[0][2][1], wrd[0][3][0], wrd[0][3][1]});
    pa[2] = __builtin_bit_cast(bf16x8, (u32x4){wrd[1][0][0], wrd[1][0][1], wrd[1][1][0], wrd[1][1][1]});
    pa[3] = __builtin_bit_cast(bf16x8, (u32x4){wrd[1][2][0], wrd[1][2][1], wrd[1][3][0], wrd[1][3][1]});

    // O += P @ V ; l += P @ ones (row-sum lands aligned with oacc rows)
    __builtin_amdgcn_s_setprio(1);
#pragma unroll
    for (int ks = 0; ks < 4; ++ks) {
      bf16x8 vf0 = *(const bf16x8*)&Vt[cur][c][ks * 16 + hi * 8];
      bf16x8 vf1 = *(const bf16x8*)&Vt[cur][32 + c][ks * 16 + hi * 8];
      oacc[0] = __builtin_amdgcn_mfma_f32_32x32x16_bf16(pa[ks], vf0, oacc[0], 0, 0, 0);
      oacc[1] = __builtin_amdgcn_mfma_f32_32x32x16_bf16(pa[ks], vf1, oacc[1], 0, 0, 0);
      oacc_l  = __builtin_amdgcn_mfma_f32_32x32x16_bf16(pa[ks], onesv, oacc_l, 0, 0, 0);
    }
    __builtin_amdgcn_s_setprio(0);
    __syncthreads();
  }

  // epilogue: inv = 1/l, perfectly aligned with O rows -- no shuffles
#pragma unroll
  for (int v = 0; v < 16; ++v) {
    const float inv = 1.0f / oacc_l[v];
    const int q = (v & 3) + 8 * (v >> 2) + 4 * hi;
    const int tq = qt * 128 + w * 32 + q;
    const size_t gbase = ((size_t)((b * T_ + tq) * H_ + h)) * D_;
    Yb[gbase + c]      = f2bf(oacc[0][v] * inv);
    Yb[gbase + 32 + c] = f2bf(oacc[1][v] * inv);
  }
}

extern "C" void kernel_launch(void* const* d_in, const int* in_sizes, int n_in,
                              void* d_out, int out_size, void* d_ws, size_t ws_size,
                              hipStream_t stream) {
  const float* x    = (const float*)d_in[0];
  const float* cosb = (const float*)d_in[1];
  const float* sinb = (const float*)d_in[2];
  const float* Wq   = (const float*)d_in[3];
  const float* Wk   = (const float*)d_in[4];
  const float* Wv   = (const float*)d_in[5];
  const float* Wo   = (const float*)d_in[6];
  float* out = (float*)d_out;

  const size_t NE = (size_t)B_ * T_ * C_;  // 8M elements
  const int CC = C_ * C_;                  // 1M elements
  // workspace (~72 MB): xb,qb,kb,vtb bf16 (64 MB) + wqkv (6 MB) + wob (2 MB)
  u16* xb   = (u16*)d_ws;
  u16* qb   = xb + NE;
  u16* kb   = qb + NE;
  u16* vtb  = kb + NE;   // V transposed + slot-permuted: [(b*H+h)*D + d][T]
  u16* wqkv = vtb + NE;
  u16* wob  = wqkv + 3 * (size_t)CC;
  u16* yb   = xb;  // xb dead after QKV GEMM; reuse for attention output

  const int M = B_ * T_;  // 8192

  const int NXB = (int)(NE / 1024);          // 8192
  const int NWB = 4 * (CC / 1024);           // 4096
  cvt_all<<<NXB + NWB, 256, 0, stream>>>(x, Wq, Wk, Wv, Wo, xb, wqkv, wob);

  dim3 qg(12, M / 128), gb(512);
  gemm_qkv<<<qg, gb, 0, stream>>>(xb, wqkv, qb, kb, vtb, cosb, sinb, M, C_);

  dim3 fg(B_ * H_, T_ / 128);
  flash_mfma<<<fg, 256, 0, stream>>>(qb, kb, vtb, yb);

  dim3 og(C_ / 256, M / 128);
  gemm_out<<<og, gb, 0, stream>>>(yb, wob, out, M, C_, C_);
}

// Round 6
// 294.218 us; speedup vs baseline: 1.0635x; 1.0503x over previous
//
#include <hip/hip_runtime.h>

#define B_ 4
#define T_ 2048
#define C_ 1024
#define H_ 16
#define D_ 64
#define EPS_ 1.1920929e-07f
#define LOG2E_ 1.4426950408889634f

typedef __attribute__((ext_vector_type(8))) short bf16x8;
typedef __attribute__((ext_vector_type(4))) float f32x4;
typedef __attribute__((ext_vector_type(16))) float f32x16;
typedef unsigned short u16;
typedef unsigned int u32;
typedef __attribute__((ext_vector_type(4))) u32 u32x4;

__device__ inline u16 f2bf(float f) {
  unsigned u = __float_as_uint(f);
  unsigned r = (u + 0x7fffu + ((u >> 16) & 1u)) >> 16;
  return (u16)r;
}

// async global->LDS, 16B per lane (dest = wave-uniform base + lane*16)
__device__ __forceinline__ void gload16(const void* g, void* l) {
  __builtin_amdgcn_global_load_lds(
      (__attribute__((address_space(1))) void*)g,
      (__attribute__((address_space(3))) void*)l, 16, 0, 0);
}

// ---------------- all f32->bf16 conversions in ONE launch ----------------
__global__ __launch_bounds__(256) void cvt_all(const float* __restrict__ x,
                                               const float* __restrict__ wq,
                                               const float* __restrict__ wk,
                                               const float* __restrict__ wv,
                                               const float* __restrict__ wo,
                                               u16* __restrict__ xb,
                                               u16* __restrict__ wqkv,
                                               u16* __restrict__ wob) {
  const int NXB = (int)((size_t)B_ * T_ * C_ / 1024);  // 8192
  const int WB = (C_ * C_) / 1024;                     // 1024
  const int bid = blockIdx.x;
  const float* src;
  u16* dst;
  int i;
  if (bid < NXB) {
    src = x; dst = xb; i = bid * 1024 + threadIdx.x * 4;
  } else {
    const int wb = bid - NXB;
    const int t = wb / WB;
    const int r = wb - t * WB;
    src = (t == 0) ? wq : (t == 1) ? wk : (t == 2) ? wv : wo;
    dst = (t == 3) ? wob : (wqkv + (size_t)t * (C_ * C_));
    i = r * 1024 + threadIdx.x * 4;
  }
  float4 v = *(const float4*)&src[i];
  ushort4 o;
  o.x = f2bf(v.x); o.y = f2bf(v.y); o.z = f2bf(v.z); o.w = f2bf(v.w);
  *(ushort4*)&dst[i] = o;
}

// ---------------- fused QKV GEMM: [Q|K|V] = X @ Wqkv^T + epilogues ----------------
// 128x256 tile, BK=64, 8 waves, dbuf LDS, one barrier/K-step.
// T2 LDS swizzle (rule #21 pairing): linear gload_lds dest + inverse-swizzled
// GLOBAL source col ((lane&7)^(lane>>3))*8 + XOR on ds_read (ko ^ (r&7)<<3).
// Breaks the 16-way row-stride-128B bank conflict on fragment reads.
// bx: 0..3 -> Q (rope+rms, *scale*log2e), 4..7 -> K, 8..11 -> V (transposed+slot-perm).
__global__ __launch_bounds__(512) void gemm_qkv(const u16* __restrict__ X,
                                                const u16* __restrict__ W,
                                                u16* __restrict__ qb,
                                                u16* __restrict__ kb,
                                                u16* __restrict__ vtb,
                                                const float* __restrict__ cs,
                                                const float* __restrict__ sn,
                                                int M, int K) {
  __shared__ short As[2][128 * 64];
  __shared__ short Bs[2][256 * 64];
  const int tid = threadIdx.x;
  const int lane = tid & 63;
  const int wid = tid >> 6;           // 0..7
  const int wm = wid >> 2, wn = wid & 3;
  const int bx = blockIdx.x, by = blockIdx.y;
  const int m0 = by * 128, n0 = bx * 256;
  const int w8 = wid * 8;
  const int lrow = lane >> 3;         // 0..7
  const int scol = ((lane & 7) ^ lrow) * 8;  // inverse-swizzled source col (u16)

  f32x4 acc[4][4];
#pragma unroll
  for (int mi = 0; mi < 4; ++mi)
#pragma unroll
    for (int ni = 0; ni < 4; ++ni)
      acc[mi][ni] = (f32x4){0.f, 0.f, 0.f, 0.f};

  const int r = lane & 15;
  const int quad = lane >> 4;
  const int rx = (r & 7) << 3;        // read-side XOR (u16 units)

  // prologue: stage tile 0 into buf 0
#pragma unroll
  for (int ra = 0; ra < 2; ++ra)
    gload16(&X[(size_t)(m0 + ra * 64 + w8 + lrow) * K + scol], &As[0][(ra * 64 + w8) * 64]);
#pragma unroll
  for (int rb = 0; rb < 4; ++rb)
    gload16(&W[(size_t)(n0 + rb * 64 + w8 + lrow) * K + scol], &Bs[0][(rb * 64 + w8) * 64]);
  __syncthreads();

#pragma unroll 2
  for (int it = 0; it < 16; ++it) {   // K = 1024 = 16 * 64
    const int cur = it & 1;
    const int kt = it * 64;
    if (it + 1 < 16) {                // stage next tile into alternate buffer
      const int nb = cur ^ 1;
#pragma unroll
      for (int ra = 0; ra < 2; ++ra)
        gload16(&X[(size_t)(m0 + ra * 64 + w8 + lrow) * K + kt + 64 + scol], &As[nb][(ra * 64 + w8) * 64]);
#pragma unroll
      for (int rb = 0; rb < 4; ++rb)
        gload16(&W[(size_t)(n0 + rb * 64 + w8 + lrow) * K + kt + 64 + scol], &Bs[nb][(rb * 64 + w8) * 64]);
    }
#pragma unroll
    for (int kc = 0; kc < 2; ++kc) {
      const int ko = (kc * 32 + quad * 8) ^ rx;   // swizzled read col
      bf16x8 a[4], b[4];
#pragma unroll
      for (int mi = 0; mi < 4; ++mi)
        a[mi] = *(const bf16x8*)&As[cur][(wm * 64 + mi * 16 + r) * 64 + ko];
#pragma unroll
      for (int ni = 0; ni < 4; ++ni)
        b[ni] = *(const bf16x8*)&Bs[cur][(wn * 64 + ni * 16 + r) * 64 + ko];
#pragma unroll
      for (int mi = 0; mi < 4; ++mi)
#pragma unroll
        for (int ni = 0; ni < 4; ++ni)
          acc[mi][ni] = __builtin_amdgcn_mfma_f32_16x16x32_bf16(a[mi], b[ni], acc[mi][ni], 0, 0, 0);
    }
    __syncthreads();                  // drains vmcnt -> staged tile visible
  }

  const int which = bx >> 2;                 // 0=Q 1=K 2=V
  const int c0 = (bx & 3) * 256 + wn * 64;   // column within tensor (one head/wave)

  if (which < 2) {
    u16* dst = (which == 0) ? qb : kb;
    // fused RoPE + RMSNorm; d = ni*16+r, pair (d,d+32) = (ni,ni+2) in-lane
#pragma unroll
    for (int mi = 0; mi < 4; ++mi)
#pragma unroll
      for (int j = 0; j < 4; ++j) {
        const int gr = m0 + wm * 64 + mi * 16 + quad * 4 + j;
        const int t = gr & (T_ - 1);
        float o[4];
#pragma unroll
        for (int ni = 0; ni < 2; ++ni) {
          const float c = cs[t * 32 + ni * 16 + r];
          const float s = sn[t * 32 + ni * 16 + r];
          const float x1 = acc[mi][ni][j], x2 = acc[mi][ni + 2][j];
          o[ni]     = x1 * c + x2 * s;
          o[ni + 2] = x2 * c - x1 * s;
        }
        float sq = o[0] * o[0] + o[1] * o[1] + o[2] * o[2] + o[3] * o[3];
        sq += __shfl_xor(sq, 1, 64);
        sq += __shfl_xor(sq, 2, 64);
        sq += __shfl_xor(sq, 4, 64);
        sq += __shfl_xor(sq, 8, 64);
        float rn = rsqrtf(sq * (1.0f / 64.0f) + EPS_);
        if (which == 0) rn *= 0.125f * LOG2E_;  // fold attn scale AND log2(e) into Q
#pragma unroll
        for (int ni = 0; ni < 4; ++ni)
          dst[(size_t)gr * C_ + c0 + ni * 16 + r] = f2bf(o[ni] * rn);
      }
  } else {
    // V: transposed + slot-permuted store. head h, d = ni*16+r.
    // key-in-tile = mi*16 + quad*4 + j -> slot = mi*16 + (j>>1)*8 + quad*2 + (j&1)
    const int h = (bx & 3) * 4 + wn;
    const int gr0 = m0 + wm * 64;
    const int bb = gr0 >> 11;         // batch (T_=2048)
    const int tbase = gr0 & (T_ - 1); // multiple of 64
#pragma unroll
    for (int ni = 0; ni < 4; ++ni) {
      const int d = ni * 16 + r;
      u16* rowp = &vtb[((size_t)((bb * H_ + h) * D_ + d)) * T_ + tbase];
#pragma unroll
      for (int mi = 0; mi < 4; ++mi) {
        u32 lo, hi2;
        asm("v_cvt_pk_bf16_f32 %0, %1, %2" : "=v"(lo) : "v"(acc[mi][ni][0]), "v"(acc[mi][ni][1]));
        asm("v_cvt_pk_bf16_f32 %0, %1, %2" : "=v"(hi2) : "v"(acc[mi][ni][2]), "v"(acc[mi][ni][3]));
        u16* p = rowp + mi * 16 + quad * 2;
        *(u32*)&p[0] = lo;
        *(u32*)&p[8] = hi2;
      }
    }
  }
}

// ---------------- output GEMM: out = Y @ Wo^T (fp32 out) ----------------
// same structure + same T2 swizzle. Grid 4x64 = 256 = 1/CU.
__global__ __launch_bounds__(512) void gemm_out(const u16* __restrict__ X,
                                                const u16* __restrict__ W,
                                                float* __restrict__ Y,
                                                int M, int N, int K) {
  __shared__ short As[2][128 * 64];
  __shared__ short Bs[2][256 * 64];
  const int tid = threadIdx.x;
  const int lane = tid & 63;
  const int wid = tid >> 6;
  const int wm = wid >> 2, wn = wid & 3;
  const int m0 = blockIdx.y * 128, n0 = blockIdx.x * 256;
  const int w8 = wid * 8;
  const int lrow = lane >> 3;
  const int scol = ((lane & 7) ^ lrow) * 8;

  f32x4 acc[4][4];
#pragma unroll
  for (int mi = 0; mi < 4; ++mi)
#pragma unroll
    for (int ni = 0; ni < 4; ++ni)
      acc[mi][ni] = (f32x4){0.f, 0.f, 0.f, 0.f};

  const int r = lane & 15;
  const int quad = lane >> 4;
  const int rx = (r & 7) << 3;

#pragma unroll
  for (int ra = 0; ra < 2; ++ra)
    gload16(&X[(size_t)(m0 + ra * 64 + w8 + lrow) * K + scol], &As[0][(ra * 64 + w8) * 64]);
#pragma unroll
  for (int rb = 0; rb < 4; ++rb)
    gload16(&W[(size_t)(n0 + rb * 64 + w8 + lrow) * K + scol], &Bs[0][(rb * 64 + w8) * 64]);
  __syncthreads();

#pragma unroll 2
  for (int it = 0; it < 16; ++it) {
    const int cur = it & 1;
    const int kt = it * 64;
    if (it + 1 < 16) {
      const int nb = cur ^ 1;
#pragma unroll
      for (int ra = 0; ra < 2; ++ra)
        gload16(&X[(size_t)(m0 + ra * 64 + w8 + lrow) * K + kt + 64 + scol], &As[nb][(ra * 64 + w8) * 64]);
#pragma unroll
      for (int rb = 0; rb < 4; ++rb)
        gload16(&W[(size_t)(n0 + rb * 64 + w8 + lrow) * K + kt + 64 + scol], &Bs[nb][(rb * 64 + w8) * 64]);
    }
#pragma unroll
    for (int kc = 0; kc < 2; ++kc) {
      const int ko = (kc * 32 + quad * 8) ^ rx;
      bf16x8 a[4], b[4];
#pragma unroll
      for (int mi = 0; mi < 4; ++mi)
        a[mi] = *(const bf16x8*)&As[cur][(wm * 64 + mi * 16 + r) * 64 + ko];
#pragma unroll
      for (int ni = 0; ni < 4; ++ni)
        b[ni] = *(const bf16x8*)&Bs[cur][(wn * 64 + ni * 16 + r) * 64 + ko];
#pragma unroll
      for (int mi = 0; mi < 4; ++mi)
#pragma unroll
        for (int ni = 0; ni < 4; ++ni)
          acc[mi][ni] = __builtin_amdgcn_mfma_f32_16x16x32_bf16(a[mi], b[ni], acc[mi][ni], 0, 0, 0);
    }
    __syncthreads();
  }

#pragma unroll
  for (int mi = 0; mi < 4; ++mi)
#pragma unroll
    for (int ni = 0; ni < 4; ++ni) {
      const int gc = n0 + wn * 64 + ni * 16 + r;
#pragma unroll
      for (int j = 0; j < 4; ++j) {
        const int gr = m0 + wm * 64 + mi * 16 + quad * 4 + j;
        Y[(size_t)gr * N + gc] = acc[mi][ni][j];
      }
    }
}

// ---------------- MFMA flash attention, swapped-QK 32x32x16, in-register P ----------------
// s = mfma(K,Q): lane (hi,c) holds P[key][query=c]; softmax lane-local.
// P -> PV A-operand via 16 cvt_pk + 8 permlane32_swap (no LDS round-trip).
// l accumulated by a ones-column MFMA -> epilogue has ZERO shuffles.
// Double-buffered K/V, one barrier/tile; unroll-2 makes buffer offsets static.
__global__ __launch_bounds__(256) void flash_mfma(const u16* __restrict__ Qb,
                                                  const u16* __restrict__ Kb,
                                                  const u16* __restrict__ Vtb,
                                                  u16* __restrict__ Yb) {
  __shared__ u16 Ks[2][64][72];
  __shared__ u16 Vt[2][64][72];   // Vt[buf][d][slot]
  const int tid = threadIdx.x;
  const int lane = tid & 63;
  const int w = tid >> 6;
  const int c = lane & 31;        // QK: query col; PV: d col
  const int hi = lane >> 5;
  const int bh = blockIdx.x, qt = blockIdx.y;
  const int b = bh >> 4, h = bh & 15;
  const int srow = lane;          // K staging row (key)
  const int sd0 = w * 16;         // K staging d-offset
  const int vrow = tid >> 2;      // V staging d row 0..63
  const int vco = (tid & 3) * 16; // V staging slot offset

  const u16* kbase = Kb + ((size_t)(b * T_ + srow) * H_ + h) * D_ + sd0;
  const u16* vbase = Vtb + ((size_t)(bh * 64 + vrow)) * T_ + vco;
  const int KSTRIDE = 64 * H_ * D_;  // u16 elems per 64-key tile

  // issue K/V tile-0 loads first (hide latency under Q staging)
  bf16x8 k0, k1, v0, v1;
  k0 = *(const bf16x8*)&kbase[0];
  k1 = *(const bf16x8*)&kbase[8];
  v0 = *(const bf16x8*)&vbase[0];
  v1 = *(const bf16x8*)&vbase[8];

  // stage Q tile (128 x 64) through the Ks buffers: 2 threads per row
  {
    const int row = tid >> 1, half = tid & 1;
    const size_t g = ((size_t)((b * T_ + qt * 128 + row) * H_ + h)) * D_ + half * 32;
    u16* qd = (row < 64) ? &Ks[0][row][half * 32] : &Ks[1][row - 64][half * 32];
    *(bf16x8*)&qd[0]  = *(const bf16x8*)&Qb[g];
    *(bf16x8*)&qd[8]  = *(const bf16x8*)&Qb[g + 8];
    *(bf16x8*)&qd[16] = *(const bf16x8*)&Qb[g + 16];
    *(bf16x8*)&qd[24] = *(const bf16x8*)&Qb[g + 24];
  }
  __syncthreads();
  // qf[ks]: B-frag, lane (hi,c) = Q[w*32+c][ks*16 + hi*8 .. +8]
  bf16x8 qf[4];
  {
    const int qr = w * 32 + c;
    const u16* qs = (qr < 64) ? &Ks[0][qr][0] : &Ks[1][qr - 64][0];
#pragma unroll
    for (int ks = 0; ks < 4; ++ks)
      qf[ks] = *(const bf16x8*)&qs[ks * 16 + hi * 8];
  }
  __syncthreads();

  // write tile 0 to buf 0, prefetch tile 1
  *(bf16x8*)&Ks[0][srow][sd0] = k0;
  *(bf16x8*)&Ks[0][srow][sd0 + 8] = k1;
  *(bf16x8*)&Vt[0][vrow][vco] = v0;
  *(bf16x8*)&Vt[0][vrow][vco + 8] = v1;
  k0 = *(const bf16x8*)&kbase[KSTRIDE];
  k1 = *(const bf16x8*)&kbase[KSTRIDE + 8];
  v0 = *(const bf16x8*)&vbase[64];
  v1 = *(const bf16x8*)&vbase[64 + 8];
  __syncthreads();

  f32x16 oacc[2], oacc_l;
  oacc[0] = (f32x16)(0.f);
  oacc[1] = (f32x16)(0.f);
  oacc_l  = (f32x16)(0.f);
  bf16x8 onesv;
#pragma unroll
  for (int i = 0; i < 8; ++i) onesv[i] = (short)0x3F80;  // bf16 1.0

  const int NT = T_ / 64;  // 32
#pragma unroll 2
  for (int t = 0; t < NT; ++t) {
    const int cur = t & 1;

    // QK^T: s[kt2] = K[kt2*32..+32] x Q  (rows=keys, cols=queries)
    f32x16 s0 = (f32x16)(0.f), s1 = (f32x16)(0.f);
    __builtin_amdgcn_s_setprio(1);
#pragma unroll
    for (int ks = 0; ks < 4; ++ks) {
      bf16x8 kf0 = *(const bf16x8*)&Ks[cur][c][ks * 16 + hi * 8];
      bf16x8 kf1 = *(const bf16x8*)&Ks[cur][32 + c][ks * 16 + hi * 8];
      s0 = __builtin_amdgcn_mfma_f32_32x32x16_bf16(kf0, qf[ks], s0, 0, 0, 0);
      s1 = __builtin_amdgcn_mfma_f32_32x32x16_bf16(kf1, qf[ks], s1, 0, 0, 0);
    }
    __builtin_amdgcn_s_setprio(0);

    // stage next tile into alternate buffer; prefetch tile t+2
    if (t + 1 < NT) {
      const int nxt = cur ^ 1;
      *(bf16x8*)&Ks[nxt][srow][sd0] = k0;
      *(bf16x8*)&Ks[nxt][srow][sd0 + 8] = k1;
      *(bf16x8*)&Vt[nxt][vrow][vco] = v0;
      *(bf16x8*)&Vt[nxt][vrow][vco + 8] = v1;
      if (t + 2 < NT) {
        const int gk = (t + 2) * KSTRIDE;
        k0 = *(const bf16x8*)&kbase[gk];
        k1 = *(const bf16x8*)&kbase[gk + 8];
        const int gv = (t + 2) * 64;
        v0 = *(const bf16x8*)&vbase[gv];
        v1 = *(const bf16x8*)&vbase[gv + 8];
      }
    }

    // softmax: p = exp2(s) (scale+log2e folded into Q); pack pairs; swap halves.
    u32 wrd[2][4][2];
#pragma unroll
    for (int m = 0; m < 4; ++m)
#pragma unroll
      for (int p = 0; p < 2; ++p) {
        float a0 = __builtin_amdgcn_exp2f(s0[m * 4 + p * 2]);
        float a1 = __builtin_amdgcn_exp2f(s0[m * 4 + p * 2 + 1]);
        float b0 = __builtin_amdgcn_exp2f(s1[m * 4 + p * 2]);
        float b1 = __builtin_amdgcn_exp2f(s1[m * 4 + p * 2 + 1]);
        asm("v_cvt_pk_bf16_f32 %0, %1, %2" : "=v"(wrd[0][m][p]) : "v"(a0), "v"(a1));
        asm("v_cvt_pk_bf16_f32 %0, %1, %2" : "=v"(wrd[1][m][p]) : "v"(b0), "v"(b1));
      }
#pragma unroll
    for (int kt2 = 0; kt2 < 2; ++kt2)
#pragma unroll
      for (int m = 0; m < 4; ++m)
        asm("v_permlane32_swap_b32 %0, %1" : "+v"(wrd[kt2][m][0]), "+v"(wrd[kt2][m][1]));

    bf16x8 pa[4];
    pa[0] = __builtin_bit_cast(bf16x8, (u32x4){wrd[0][0][0], wrd[0][0][1], wrd[0][1][0], wrd[0][1][1]});
    pa[1] = __builtin_bit_cast(bf16x8, (u32x4){wrd[0][2][0], wrd[0][2][1], wrd[0][3][0], wrd[0][3][1]});
    pa[2] = __builtin_bit_cast(bf16x8, (u32x4){wrd[1][0][0], wrd[1][0][1], wrd[1][1][0], wrd[1][1][1]});
    pa[3] = __builtin_bit_cast(bf16x8, (u32x4){wrd[1][2][0], wrd[1][2][1], wrd[1][3][0], wrd[1][3][1]});

    // O += P @ V ; l += P @ ones (row-sum lands aligned with oacc rows)
    __builtin_amdgcn_s_setprio(1);
#pragma unroll
    for (int ks = 0; ks < 4; ++ks) {
      bf16x8 vf0 = *(const bf16x8*)&Vt[cur][c][ks * 16 + hi * 8];
      bf16x8 vf1 = *(const bf16x8*)&Vt[cur][32 + c][ks * 16 + hi * 8];
      oacc[0] = __builtin_amdgcn_mfma_f32_32x32x16_bf16(pa[ks], vf0, oacc[0], 0, 0, 0);
      oacc[1] = __builtin_amdgcn_mfma_f32_32x32x16_bf16(pa[ks], vf1, oacc[1], 0, 0, 0);
      oacc_l  = __builtin_amdgcn_mfma_f32_32x32x16_bf16(pa[ks], onesv, oacc_l, 0, 0, 0);
    }
    __builtin_amdgcn_s_setprio(0);
    __syncthreads();
  }

  // epilogue: inv = 1/l, perfectly aligned with O rows -- no shuffles
#pragma unroll
  for (int v = 0; v < 16; ++v) {
    const float inv = 1.0f / oacc_l[v];
    const int q = (v & 3) + 8 * (v >> 2) + 4 * hi;
    const int tq = qt * 128 + w * 32 + q;
    const size_t gbase = ((size_t)((b * T_ + tq) * H_ + h)) * D_;
    Yb[gbase + c]      = f2bf(oacc[0][v] * inv);
    Yb[gbase + 32 + c] = f2bf(oacc[1][v] * inv);
  }
}

extern "C" void kernel_launch(void* const* d_in, const int* in_sizes, int n_in,
                              void* d_out, int out_size, void* d_ws, size_t ws_size,
                              hipStream_t stream) {
  const float* x    = (const float*)d_in[0];
  const float* cosb = (const float*)d_in[1];
  const float* sinb = (const float*)d_in[2];
  const float* Wq   = (const float*)d_in[3];
  const float* Wk   = (const float*)d_in[4];
  const float* Wv   = (const float*)d_in[5];
  const float* Wo   = (const float*)d_in[6];
  float* out = (float*)d_out;

  const size_t NE = (size_t)B_ * T_ * C_;  // 8M elements
  const int CC = C_ * C_;                  // 1M elements
  // workspace (~72 MB): xb,qb,kb,vtb bf16 (64 MB) + wqkv (6 MB) + wob (2 MB)
  u16* xb   = (u16*)d_ws;
  u16* qb   = xb + NE;
  u16* kb   = qb + NE;
  u16* vtb  = kb + NE;   // V transposed + slot-permuted: [(b*H+h)*D + d][T]
  u16* wqkv = vtb + NE;
  u16* wob  = wqkv + 3 * (size_t)CC;
  u16* yb   = xb;  // xb dead after QKV GEMM; reuse for attention output

  const int M = B_ * T_;  // 8192

  const int NXB = (int)(NE / 1024);          // 8192
  const int NWB = 4 * (CC / 1024);           // 4096
  cvt_all<<<NXB + NWB, 256, 0, stream>>>(x, Wq, Wk, Wv, Wo, xb, wqkv, wob);

  dim3 qg(12, M / 128), gb(512);
  gemm_qkv<<<qg, gb, 0, stream>>>(xb, wqkv, qb, kb, vtb, cosb, sinb, M, C_);

  dim3 fg(B_ * H_, T_ / 128);
  flash_mfma<<<fg, 256, 0, stream>>>(qb, kb, vtb, yb);

  dim3 og(C_ / 256, M / 128);
  gemm_out<<<og, gb, 0, stream>>>(yb, wob, out, M, C_, C_);
}